// Round 13
// baseline (188.114 us; speedup 1.0000x reference)
//
#include <hip/hip_runtime.h>

typedef unsigned int u32;
typedef unsigned long long u64;

#define A_TOT    159882
#define BS       2
#define KTOP     1000
#define CAND_CAP 4096
#define HB       4096        // 12-bit histogram buckets per segment
#define ABLK     4096        // anchors per hist/compact block
#define NBH      40          // blocks per image (40*4096 >= A_TOT)
#define EPT      16          // ABLK/256

// ---- workspace layout (bytes) ----
static const size_t CUT_OFF      = 131072;    // (unused, kept for zero range)
static const size_t CCNT_OFF     = 131104;    // u32[8]
static const size_t MAXC_OFF     = 131136;    // u32[2]
static const size_t NV_OFF       = 131144;    // u32[10]
static const size_t CHUNKANY_OFF = 131200;    // u64[10*16]
static const size_t ZERO_END     = 132480;    // control zero range [CUT_OFF, ZERO_END)
static const size_t CAND_OFF     = 132480;    // u64[8*4096]
static const size_t LKEY2_OFF    = 394624;    // u64[10*1024]
static const size_t LBOX_OFF     = 476544;    // float4[10*1024]
static const size_t LSC_OFF      = 640384;    // float[10*1024]
static const size_t RANK_OFF     = 681344;    // u32[10*1024]
static const size_t MASK_OFF     = 759168;    // u64[10*16000] -> end 2,039,168
static const size_t SLICE_OFF    = 2039296;   // u32[2*40*2*4096] = 2.62 MB (no zeroing needed)
// total ~4.66 MB

__device__ __forceinline__ int level_of(int a) {
  if (a < 120000) return 0;
  if (a < 150000) return 1;
  if (a < 157500) return 2;
  if (a < 159375) return 3;
  return 4;
}

// monotone decreasing transform: smaller d == larger score; d(-inf)=0xFF800000
__device__ __forceinline__ u32 dkey(float s) {
  u32 b = __float_as_uint(s);
  return (b & 0x80000000u) ? b : (~b & 0x7FFFFFFFu);
}
// exact inverse of dkey
__device__ __forceinline__ float dkey_inv(u32 d) {
  u32 b = (d & 0x80000000u) ? d : (~d & 0x7FFFFFFFu);
  return __uint_as_float(b);
}

// bit-exact replica of reference decode + clip + min-size check
__device__ __forceinline__ void decode_clip(const float* __restrict__ pred,
                                            const float* __restrict__ anch,
                                            const float* __restrict__ vs,
                                            int b, int a,
                                            float& x1c, float& y1c, float& x2c, float& y2c,
                                            bool& valid) {
  const float* pp = pred + ((size_t)b * A_TOT + (size_t)a) * 4;
  const float* aa = anch + (size_t)a * 4;
  float ax1 = aa[0], ay1 = aa[1], ax2 = aa[2], ay2 = aa[3];
  float px = pp[0], py = pp[1], pw = pp[2], ph = pp[3];
  float aw  = __fsub_rn(ax2, ax1);
  float ah  = __fsub_rn(ay2, ay1);
  float acx = __fadd_rn(ax1, __fmul_rn(0.5f, aw));
  float acy = __fadd_rn(ay1, __fmul_rn(0.5f, ah));
  float cx  = __fadd_rn(acx, __fmul_rn(px, aw));
  float cy  = __fadd_rn(acy, __fmul_rn(py, ah));
  float w   = __fmul_rn(expf(pw), aw);
  float h   = __fmul_rn(expf(ph), ah);
  float x1  = __fsub_rn(cx, __fmul_rn(0.5f, w));
  float y1  = __fsub_rn(cy, __fmul_rn(0.5f, h));
  float x2  = __fadd_rn(x1, w);
  float y2  = __fadd_rn(y1, h);
  float Wv = vs[b * 2 + 0], Hv = vs[b * 2 + 1];
  x1c = fminf(fmaxf(x1, 0.0f), Wv);
  y1c = fminf(fmaxf(y1, 0.0f), Hv);
  x2c = fminf(fmaxf(x2, 0.0f), Wv);
  y2c = fminf(fmaxf(y2, 0.0f), Hv);
  valid = (__fsub_rn(x2c, x1c) > 0.001f) && (__fsub_rn(y2c, y1c) > 0.001f);
}

__device__ __forceinline__ void bitonic_u64(u64* arr, int N, int t, int nt) {
  for (int k = 2; k <= N; k <<= 1) {
    for (int j = k >> 1; j > 0; j >>= 1) {
      __syncthreads();
      for (int i = t; i < N; i += nt) {
        int ixj = i ^ j;
        if (ixj > i) {
          u64 x = arr[i], y = arr[ixj];
          bool up = ((i & k) == 0);
          if (up ? (x > y) : (x < y)) { arr[i] = y; arr[ixj] = x; }
        }
      }
    }
  }
  __syncthreads();
}

__device__ __forceinline__ u64 shfl_xor_u64(u64 x, int lanemask) {
  u32 lo = (u32)x, hi = (u32)(x >> 32);
  lo = (u32)__shfl_xor((int)lo, lanemask);
  hi = (u32)__shfl_xor((int)hi, lanemask);
  return ((u64)hi << 32) | (u64)lo;
}

// bitonic sort of 2048 u64 keys: 2/thread over 1024 threads.
__device__ __forceinline__ u64* regsort2048x(u64 v[2], int tid, u64* bufA, u64* bufB) {
  u64* bufs[2] = {bufA, bufB};
  int cur = 0;
  for (int k = 2; k <= 2048; k <<= 1) {
    for (int j = k >> 1; j > 0; j >>= 1) {
      if (j == 1) {
        bool up = (((2 * tid) & k) == 0);
        u64 a = v[0], b2 = v[1];
        bool sw = up ? (a > b2) : (a < b2);
        if (sw) { v[0] = b2; v[1] = a; }
      } else if (j <= 64) {
        int dl = j >> 1;
        bool up = (((2 * tid) & k) == 0);
        bool low = ((tid & dl) == 0);
        bool keepmin = (low == up);
#pragma unroll
        for (int e = 0; e < 2; ++e) {
          u64 o = shfl_xor_u64(v[e], dl);
          v[e] = keepmin ? (v[e] < o ? v[e] : o) : (v[e] > o ? v[e] : o);
        }
      } else {
        u64* B = bufs[cur]; cur ^= 1;
        B[2 * tid] = v[0]; B[2 * tid + 1] = v[1];
        __syncthreads();
#pragma unroll
        for (int e = 0; e < 2; ++e) {
          int i = 2 * tid + e, p = i ^ j;
          u64 o = B[p];
          bool up = ((i & k) == 0);
          bool keepmin = ((i < p) == up);
          v[e] = keepmin ? (v[e] < o ? v[e] : o) : (v[e] > o ? v[e] : o);
        }
      }
    }
  }
  u64* B = bufs[cur];
  B[2 * tid] = v[0]; B[2 * tid + 1] = v[1];
  __syncthreads();
  return B;
}

// ---------- 1) 12-bit histogram -> private per-block slices (no atomics, no pre-zero) ----------
__global__ void k_hist12(const float* __restrict__ obj, char* __restrict__ ws) {
  __shared__ u32 h[2 * HB];   // 32 KB
  int tid = threadIdx.x;
  int b = blockIdx.x / NBH, loc = blockIdx.x % NBH;
  if (blockIdx.x == 0) {      // zero the small control region (consumed by later dispatches)
    for (int i = tid; (size_t)i * 4 < (ZERO_END - CUT_OFF); i += 256)
      ((u32*)(ws + CUT_OFF))[i] = 0u;
  }
  int start = loc * ABLK;
  int l0 = level_of(start);
  if (l0 >= 4) return;
  for (int i = tid; i < 2 * HB; i += 256) h[i] = 0u;
  __syncthreads();
  for (int it = 0; it < EPT; ++it) {
    int a = start + it * 256 + tid;
    if (a < A_TOT) {
      int l = level_of(a);
      if (l < 4) {
        u32 d = dkey(obj[(size_t)b * A_TOT + a]);
        atomicAdd(&h[(u32)(l - l0) * HB + (d >> 20)], 1u);
      }
    }
  }
  __syncthreads();
  int lend = level_of(min(start + ABLK - 1, A_TOT - 1));
  int nseg = ((l0 + 1 <= lend) && (l0 + 1 < 4)) ? 2 : 1;
  for (int s = 0; s < nseg; ++s) {
    u32* gs = (u32*)(ws + SLICE_OFF) + ((size_t)(b * NBH + loc) * 2 + s) * HB;
    for (int i = tid; i < HB; i += 256) gs[i] = h[s * HB + i];   // plain coalesced stores
  }
}

// ---------- 2) slice-sum cutoff + block-aggregated candidate append ----------
__global__ void k_compactsel(const float* __restrict__ obj, char* __restrict__ ws) {
  __shared__ u32 histL[HB];   // 16 KB
  __shared__ u32 scan[256];
  __shared__ u32 cutv[2];
  __shared__ u32 lcnt[2], gbase[2];
  int tid = threadIdx.x, lane = tid & 63;
  int b = blockIdx.x / NBH, loc = blockIdx.x % NBH;
  int start = loc * ABLK;
  int l0 = level_of(start);
  if (l0 >= 4) return;
  int lend = level_of(min(start + ABLK - 1, A_TOT - 1));
  int nseg = ((l0 + 1 <= lend) && (l0 + 1 < 4)) ? 2 : 1;
  if (tid < 2) lcnt[tid] = 0;
  // cutoff per segment: sum contributing slices (coalesced), identical integer counts
  for (int s = 0; s < nseg; ++s) {
    int segl = l0 + s;
    u32 acc16[16];
#pragma unroll
    for (int q = 0; q < 16; ++q) acc16[q] = 0;
    for (int bk = 0; bk < NBH; ++bk) {
      int bs = bk * ABLK;
      int bl0 = level_of(bs);
      if (bl0 >= 4) continue;
      int blend = level_of(min(bs + ABLK - 1, A_TOT - 1));
      int bnseg = ((bl0 + 1 <= blend) && (bl0 + 1 < 4)) ? 2 : 1;
      int si = (bl0 == segl) ? 0 : ((bnseg == 2 && bl0 + 1 == segl) ? 1 : -1);
      if (si < 0) continue;
      const u32* sp = (const u32*)(ws + SLICE_OFF) + ((size_t)(b * NBH + bk) * 2 + si) * HB;
#pragma unroll
      for (int q = 0; q < 16; ++q) acc16[q] += sp[tid + 256 * q];
    }
    __syncthreads();            // protect histL/scan from previous iteration's readers
#pragma unroll
    for (int q = 0; q < 16; ++q) histL[tid + 256 * q] = acc16[q];
    __syncthreads();
    u32 vals[16]; u32 acc = 0;
    for (int q = 0; q < 16; ++q) { vals[q] = histL[tid * 16 + q]; acc += vals[q]; }
    scan[tid] = acc; __syncthreads();
    for (int d = 1; d < 256; d <<= 1) {
      u32 x = (tid >= d) ? scan[tid - d] : 0u; __syncthreads();
      scan[tid] += x; __syncthreads();
    }
    u32 incl = scan[tid], prev = incl - acc;
    if (prev < KTOP && incl >= KTOP) {
      u32 run = prev; int cb = HB - 1;
      for (int q = 0; q < 16; ++q) { run += vals[q]; if (run >= KTOP) { cb = tid * 16 + q; break; } }
      cutv[s] = (u32)cb;
    }
  }
  __syncthreads();
  u32 dv[EPT], slotv[EPT], passm = 0, sim = 0;
  for (int it = 0; it < EPT; ++it) {
    int a = start + it * 256 + tid;
    bool pass = false; u32 si = 0, d = 0;
    if (a < A_TOT) {
      int l = level_of(a);
      if (l < 4) {
        si = (u32)(l - l0);
        d = dkey(obj[(size_t)b * A_TOT + a]);
        pass = (d >> 20) <= cutv[si];
      }
    }
    dv[it] = d;
    u64 mp = __ballot(pass);
    u64 m1 = __ballot(pass && si == 1);
    u64 m0 = mp & ~m1;
    u32 slot = 0;
    if (m0) {
      int ld = __builtin_ctzll(m0);
      u32 wb = 0;
      if (lane == ld) wb = atomicAdd(&lcnt[0], (u32)__popcll(m0));
      wb = __shfl(wb, ld);
      if (pass && si == 0) slot = wb + (u32)__popcll(m0 & ((1ull << lane) - 1ull));
    }
    if (m1) {
      int ld = __builtin_ctzll(m1);
      u32 wb = 0;
      if (lane == ld) wb = atomicAdd(&lcnt[1], (u32)__popcll(m1));
      wb = __shfl(wb, ld);
      if (pass && si == 1) slot = wb + (u32)__popcll(m1 & ((1ull << lane) - 1ull));
    }
    slotv[it] = slot;
    if (pass) { passm |= 1u << it; if (si) sim |= 1u << it; }
  }
  __syncthreads();
  if (tid < 2)
    gbase[tid] = lcnt[tid] ? atomicAdd((u32*)(ws + CCNT_OFF) + (b * 4 + l0 + tid), lcnt[tid]) : 0u;
  __syncthreads();
  for (int it = 0; it < EPT; ++it) {
    if ((passm >> it) & 1u) {
      int a = start + it * 256 + tid;
      u32 si = (sim >> it) & 1u;
      int seg = b * 4 + l0 + (int)si;
      u32 gslot = gbase[si] + slotv[it];
      if (gslot < CAND_CAP)
        // key = [dkey:32][anchor:18][slot:12] — slot below the anchor tie-break
        ((u64*)(ws + CAND_OFF))[(size_t)seg * CAND_CAP + gslot] =
            ((u64)dv[it] << 32) | ((u64)(u32)a << 12) | (u64)gslot;
    }
  }
}

// ---------- 3) per-(image,level): parallel gather-decode + register bitonic + compaction ----------
__global__ __launch_bounds__(1024)
void k_sortdec(const float* __restrict__ pred, const float* __restrict__ obj,
               const float* __restrict__ anch, const float* __restrict__ vs,
               char* __restrict__ ws) {
  __shared__ u64 bufAB[4096];        // 32 KB (double buffer / fallback array)
  __shared__ float4 dboxS[2048];     // 32 KB, indexed by slot
  __shared__ float dscS[2048];       // 8 KB
  __shared__ u32 validS[2048];       // 8 KB
  __shared__ u64 cm[16];
  u64* bufA = bufAB; u64* bufB = bufAB + 2048;
  int tid = threadIdx.x, lane = tid & 63, wv = tid >> 6;
  int P = blockIdx.x, b = P / 5, l = P % 5;
  int n;
  u64* S;
  if (l == 4) {
    n = 507;
    u64 v[2];
#pragma unroll
    for (int e = 0; e < 2; ++e) {
      int idx = 2 * tid + e;
      if (idx < 507) {
        int a = 159375 + idx;
        float sc = obj[(size_t)b * A_TOT + a];
        float x1, y1, x2, y2; bool valid;
        decode_clip(pred, anch, vs, b, a, x1, y1, x2, y2, valid);
        dboxS[idx] = make_float4(x1, y1, x2, y2);
        dscS[idx] = sc;
        validS[idx] = valid ? 1u : 0u;
        v[e] = ((u64)dkey(sc) << 32) | ((u64)(u32)a << 12) | (u64)idx;
      } else v[e] = ~0ull;
    }
    S = regsort2048x(v, tid, bufA, bufB);
  } else {
    n = KTOP;
    int seg = b * 4 + l;
    u32 cnt = min(((const u32*)(ws + CCNT_OFF))[seg], (u32)CAND_CAP);
    const u64* cand = (const u64*)(ws + CAND_OFF) + (size_t)seg * CAND_CAP;
    if (cnt <= 2048) {
      u64 v[2];
#pragma unroll
      for (int e = 0; e < 2; ++e) {
        int idx = 2 * tid + e;
        if (idx < (int)cnt) {
          u64 key = cand[idx];
          int a = (int)((key >> 12) & 0x3FFFFu);
          float x1, y1, x2, y2; bool valid;
          decode_clip(pred, anch, vs, b, a, x1, y1, x2, y2, valid);
          dboxS[idx] = make_float4(x1, y1, x2, y2);
          dscS[idx] = dkey_inv((u32)(key >> 32));
          validS[idx] = valid ? 1u : 0u;
          v[e] = key;
        } else v[e] = ~0ull;
      }
      S = regsort2048x(v, tid, bufA, bufB);
    } else {
      // safety fallback (statistically never taken: cnt ~= 1030)
      int N = 2048; while (N < (int)cnt) N <<= 1;
      for (int i = tid; i < N; i += 1024) bufAB[i] = (i < (int)cnt) ? cand[i] : ~0ull;
      bitonic_u64(bufAB, N, tid, 1024);
      for (int j = tid; j < KTOP; j += 1024) {
        u64 key = bufAB[j];
        int a = (int)((key >> 12) & 0x3FFFFu);
        float x1, y1, x2, y2; bool valid;
        decode_clip(pred, anch, vs, b, a, x1, y1, x2, y2, valid);
        dboxS[j] = make_float4(x1, y1, x2, y2);
        dscS[j] = dkey_inv((u32)(key >> 32));
        validS[j] = valid ? 1u : 0u;
        bufAB[j] = (key & ~0xFFFull) | (u64)j;   // rewrite slot = sorted pos
      }
      __syncthreads();
      S = bufAB;
    }
  }
  // max coord over the selected top-n (reference: max over selected boxes only)
  float m = 0.0f;
  for (int j = tid; j < n; j += 1024) {
    int slot = (int)(S[j] & 0xFFFull);
    float4 bx = dboxS[slot];
    m = fmaxf(m, fmaxf(fmaxf(bx.x, bx.y), fmaxf(bx.z, bx.w)));
  }
  for (int off = 32; off; off >>= 1) m = fmaxf(m, __shfl_xor(m, off));
  if (lane == 0) atomicMax((u32*)(ws + MAXC_OFF) + b, __float_as_uint(m));
  // stable valid-compaction, all 16 waves (wave w owns chunk w of 64)
  {
    int j = wv * 64 + lane;
    bool val = (j < n) && (validS[(int)(S[j] & 0xFFFull)] != 0u);
    u64 mask = __ballot(val);
    if (lane == 0) cm[wv] = mask;
    __syncthreads();
    int base = 0;
    for (int w2 = 0; w2 < wv; ++w2) base += __popcll(cm[w2]);
    if (val) {
      int r = base + __popcll(mask & ((1ull << lane) - 1ull));
      int slot = (int)(S[j] & 0xFFFull);
      ((u64*)(ws + LKEY2_OFF))[(size_t)P * 1024 + r] = S[j];
      ((float4*)(ws + LBOX_OFF))[(size_t)P * 1024 + r] = dboxS[slot];
      ((float*)(ws + LSC_OFF))[(size_t)P * 1024 + r] = dscS[slot];
    }
    if (tid == 0) {
      int tot = 0;
      for (int w2 = 0; w2 < 16; ++w2) tot += __popcll(cm[w2]);
      ((u32*)(ws + NV_OFF))[P] = (u32)tot;
    }
  }
}

// ---------- 4) distributed rank + LDS-staged suppression bitmask ----------
__global__ void k_maskrank(char* __restrict__ ws) {
  __shared__ float4 boxS[1024];   // 16 KB (offset applied)
  __shared__ float  areaS[1024];  //  4 KB (area of offset box)
  int tid = threadIdx.x, bid = blockIdx.x;
  int P = bid >> 6, rblk = bid & 63;
  int b = P / 5, l = P % 5;
  int n = (int)((const u32*)(ws + NV_OFF))[P];
  float M = __uint_as_float(((const u32*)(ws + MAXC_OFF))[b]);
  float maxc = __fadd_rn(M, 1.0f);
  float off = __fmul_rn((float)l, maxc);
  const float4* lbox = (const float4*)(ws + LBOX_OFF) + (size_t)P * 1024;
  for (int i = tid; i < n; i += 256) {
    float4 bx = lbox[i];
    bx.x = __fadd_rn(bx.x, off); bx.y = __fadd_rn(bx.y, off);
    bx.z = __fadd_rn(bx.z, off); bx.w = __fadd_rn(bx.w, off);
    boxS[i] = bx;
    areaS[i] = __fmul_rn(__fsub_rn(bx.z, bx.x), __fsub_rn(bx.w, bx.y));
  }
  // rank: this block's 16 elements, one per thread, 4 searches lock-step
  {
    int e = rblk * 16 + tid;
    if (tid < 16 && e < n) {
      const u64* lkey = (const u64*)(ws + LKEY2_OFF);
      const u32* nvp = (const u32*)(ws + NV_OFF);
      u64 key = lkey[(size_t)P * 1024 + e];
      const u64* base[4];
      int lo[4], hi[4], q2 = 0;
      for (int l2 = 0; l2 < 5; ++l2) {
        if (l2 == l) continue;
        base[q2] = lkey + (size_t)(b * 5 + l2) * 1024;
        lo[q2] = 0; hi[q2] = (int)nvp[b * 5 + l2];
        ++q2;
      }
      for (int step = 0; step < 11; ++step) {
#pragma unroll
        for (int q = 0; q < 4; ++q) {
          if (lo[q] < hi[q]) {
            int mid = (lo[q] + hi[q]) >> 1;
            u64 v = base[q][mid];
            if (v < key) lo[q] = mid + 1; else hi[q] = mid;
          }
        }
      }
      ((u32*)(ws + RANK_OFF))[(size_t)P * 1024 + e] =
          (u32)(e + lo[0] + lo[1] + lo[2] + lo[3]);
    }
  }
  __syncthreads();
  int i = rblk * 16 + (tid >> 4);
  int w = tid & 15;
  int W = (n + 63) >> 6;
  if (i >= n || w >= W) return;
  float4 bi = boxS[i];
  float ai = areaS[i];
  u64 word = 0;
  int j0 = w << 6;
  int jn = min(64, n - j0);
  if (jn == 64) {
#pragma unroll 4
    for (int t2 = 0; t2 < 64; ++t2) {
      int jj = (t2 + w) & 63;     // bank-conflict-free rotation
      float4 bj = boxS[j0 + jj];
      float xx1 = fmaxf(bi.x, bj.x);
      float yy1 = fmaxf(bi.y, bj.y);
      float xx2 = fminf(bi.z, bj.z);
      float yy2 = fminf(bi.w, bj.w);
      float iw = fmaxf(__fsub_rn(xx2, xx1), 0.0f);
      float ih = fmaxf(__fsub_rn(yy2, yy1), 0.0f);
      float inter = __fmul_rn(iw, ih);
      float den = __fadd_rn(__fsub_rn(__fadd_rn(ai, areaS[j0 + jj]), inter), 1e-9f);
      float iou = __fdiv_rn(inter, den);
      if (iou > 0.7f) word |= (1ull << jj);
    }
  } else {
    for (int jj = 0; jj < jn; ++jj) {
      float4 bj = boxS[j0 + jj];
      float xx1 = fmaxf(bi.x, bj.x);
      float yy1 = fmaxf(bi.y, bj.y);
      float xx2 = fminf(bi.z, bj.z);
      float yy2 = fminf(bi.w, bj.w);
      float iw = fmaxf(__fsub_rn(xx2, xx1), 0.0f);
      float ih = fmaxf(__fsub_rn(yy2, yy1), 0.0f);
      float inter = __fmul_rn(iw, ih);
      float den = __fadd_rn(__fsub_rn(__fadd_rn(ai, areaS[j0 + jj]), inter), 1e-9f);
      float iou = __fdiv_rn(inter, den);
      if (iou > 0.7f) word |= (1ull << jj);
    }
  }
  if (i >= j0 && i < j0 + 64) word &= ~(1ull << (i - j0));   // zero diagonal
  ((u64*)(ws + MASK_OFF))[(size_t)P * 16000 + (size_t)i * W + w] = word;
  if (word)
    atomicOr((u64*)(ws + CHUNKANY_OFF) + (size_t)P * 16 + (i >> 6), 1ull << (i & 63));
}

// ---------- 5) NMS scan (5 waves = 5 levels), latency-optimized + parallel emit ----------
__global__ __launch_bounds__(320)
void k_scanfin(float* __restrict__ out, char* __restrict__ ws) {
  __shared__ u64 keeps[5][16];
  __shared__ u64 kb[80];
  __shared__ u32 sb[128];
  __shared__ u32 pfx[80];
  __shared__ u32 nvs[5];
  int tid = threadIdx.x, w = tid >> 6, lane = tid & 63;
  int b = blockIdx.x;
  for (int i = tid; i < 80; i += 320) kb[i] = 0ull;
  for (int i = tid; i < 4000; i += 320) out[(size_t)b * 4000 + i] = 0.0f;
  for (int i = tid; i < 1000; i += 320) out[8000 + (size_t)b * 1000 + i] = 0.0f;
  if (tid < 5) nvs[tid] = ((const u32*)(ws + NV_OFF))[b * 5 + tid];

  int P = b * 5 + w;
  int n = (int)((const u32*)(ws + NV_OFF))[P];
  int W = (n + 63) >> 6;
  const u64* maskg = (const u64*)(ws + MASK_OFF) + (size_t)P * 16000;
  u64 ca = (lane < 16) ? ((const u64*)(ws + CHUNKANY_OFF))[(size_t)P * 16 + lane] : 0ull;
  u64 dpre[16];
#pragma unroll
  for (int c = 0; c < 16; ++c) {
    int row = (c << 6) + lane;
    dpre[c] = (c < W && row < n) ? maskg[(size_t)row * W + c] : 0ull;
  }
  u64 removed = 0ull, keepw = 0ull;
#pragma unroll
  for (int c = 0; c < 16; ++c) {
    if (c >= W) break;
    int rb = c << 6;
    int rows = min(64, n - rb);
    u64 rowsmask = (rows == 64) ? ~0ull : ((1ull << rows) - 1ull);
    u64 curw = __shfl(removed, c);
    u64 cand = ~curw & rowsmask;
    u64 ca_c = __shfl(ca, c);
    u64 keptbits;
    u64 anyrows = ca_c & cand;
    if (anyrows == 0ull) {
      keptbits = cand;
    } else {
      u64 diag = dpre[c];
      u64 diagnz = __ballot(diag != 0ull) & cand;
      if (diagnz == 0ull) {
        keptbits = cand;
      } else {
        u64 remw = curw | ~rowsmask;
        u64 kept = 0ull;
        int pos = 0;
        u64 work = diagnz;
        while (work) {
          int s = __builtin_ctzll(work); work &= work - 1;
          u64 range = (1ull << s) - (1ull << pos);
          kept |= ~remw & range;
          bool k = ((remw >> s) & 1ull) == 0ull;
          u64 dr = __shfl(diag, s);
          if (k) { kept |= 1ull << s; remw |= dr; }
          pos = s + 1;
        }
        u64 tail = (pos >= 64) ? 0ull : (~0ull << pos);
        kept |= ~remw & tail & rowsmask;
        keptbits = kept;
      }
      u64 todo = keptbits & ca_c;
      while (todo) {
        int r0 = __builtin_ctzll(todo); todo &= todo - 1;
        int r1 = -1, r2 = -1, r3 = -1;
        if (todo) { r1 = __builtin_ctzll(todo); todo &= todo - 1; }
        if (todo) { r2 = __builtin_ctzll(todo); todo &= todo - 1; }
        if (todo) { r3 = __builtin_ctzll(todo); todo &= todo - 1; }
        u64 v0 = 0, v1 = 0, v2 = 0, v3 = 0;
        if (lane < W) {
          v0 = maskg[(size_t)(rb + r0) * W + lane];
          if (r1 >= 0) v1 = maskg[(size_t)(rb + r1) * W + lane];
          if (r2 >= 0) v2 = maskg[(size_t)(rb + r2) * W + lane];
          if (r3 >= 0) v3 = maskg[(size_t)(rb + r3) * W + lane];
        }
        removed |= v0 | v1 | v2 | v3;
      }
    }
    if (lane == c) keepw |= keptbits;
  }
  if (lane < 16) keeps[w][lane] = keepw;
  __syncthreads();

  const u32* rank = (const u32*)(ws + RANK_OFF);
  for (int idx = tid; idx < 5120; idx += 320) {
    int p = idx >> 10, i = idx & 1023;
    if (i < (int)nvs[p] && ((keeps[p][i >> 6] >> (i & 63)) & 1ull)) {
      u32 r = rank[(size_t)(b * 5 + p) * 1024 + i];
      atomicOr(&kb[r >> 6], 1ull << (r & 63));
    }
  }
  __syncthreads();
  if (tid < 128) sb[tid] = (tid < 80) ? (u32)__popcll(kb[tid]) : 0u;
  __syncthreads();
  for (int d = 1; d < 128; d <<= 1) {
    u32 x = (tid < 128 && tid >= d) ? sb[tid - d] : 0u;
    __syncthreads();
    if (tid < 128) sb[tid] += x;
    __syncthreads();
  }
  if (tid < 80) pfx[tid] = sb[tid] - (u32)__popcll(kb[tid]);
  __syncthreads();
  for (int idx = tid; idx < 5120; idx += 320) {
    int p = idx >> 10, i = idx & 1023;
    if (i < (int)nvs[p] && ((keeps[p][i >> 6] >> (i & 63)) & 1ull)) {
      int Pp = b * 5 + p;
      u32 r = rank[(size_t)Pp * 1024 + i];
      u64 word = kb[r >> 6];
      int slot = (int)pfx[r >> 6] + __popcll(word & ((1ull << (r & 63)) - 1ull));
      if (slot < KTOP) {
        float4 bx = ((const float4*)(ws + LBOX_OFF))[(size_t)Pp * 1024 + i];
        float s = ((const float*)(ws + LSC_OFF))[(size_t)Pp * 1024 + i];
        float* ob = out + ((size_t)b * KTOP + slot) * 4;
        ob[0] = bx.x; ob[1] = bx.y; ob[2] = bx.z; ob[3] = bx.w;
        out[8000 + (size_t)b * KTOP + slot] = s;
      }
    }
  }
}

extern "C" void kernel_launch(void* const* d_in, const int* in_sizes, int n_in,
                              void* d_out, int out_size, void* d_ws, size_t ws_size,
                              hipStream_t stream) {
  const float* pred = (const float*)d_in[0];
  const float* obj  = (const float*)d_in[1];
  const float* anch = (const float*)d_in[2];
  const float* vs   = (const float*)d_in[3];
  float* out = (float*)d_out;
  char* ws = (char*)d_ws;
  (void)in_sizes; (void)n_in; (void)out_size; (void)ws_size;

  k_hist12    <<<BS * NBH,  256, 0, stream>>>(obj, ws);
  k_compactsel<<<BS * NBH,  256, 0, stream>>>(obj, ws);
  k_sortdec   <<<10,       1024, 0, stream>>>(pred, obj, anch, vs, ws);
  k_maskrank  <<<640,       256, 0, stream>>>(ws);
  k_scanfin   <<<2,         320, 0, stream>>>(out, ws);
}

// Round 14
// 163.300 us; speedup vs baseline: 1.1520x; 1.1520x over previous
//
#include <hip/hip_runtime.h>

typedef unsigned int u32;
typedef unsigned long long u64;

#define A_TOT    159882
#define BS       2
#define KTOP     1000
#define CAND_CAP 4096
#define HB       4096        // 12-bit histogram buckets per segment
#define ABLK     4096        // anchors per hist/compact block
#define NBH      40          // blocks per image (40*4096 >= A_TOT)
#define EPT      16          // ABLK/256

// ---- workspace layout (bytes) ----
static const size_t HIST12_OFF   = 0;         // u32[8*4096] = 128 KB (L2-resident)
static const size_t CUT_OFF      = 131072;    // u32[8]
static const size_t CCNT_OFF     = 131104;    // u32[8]
static const size_t MAXC_OFF     = 131136;    // u32[2]
static const size_t NV_OFF       = 131144;    // u32[10]
static const size_t CHUNKANY_OFF = 131200;    // u64[10*16]
static const size_t ZERO_END     = 132480;    // k_zero covers [0, ZERO_END)
static const size_t CAND_OFF     = 132480;    // u64[8*4096]
static const size_t LKEY2_OFF    = 394624;    // u64[10*1024]
static const size_t LBOX_OFF     = 476544;    // float4[10*1024]
static const size_t LSC_OFF      = 640384;    // float[10*1024]
static const size_t RANK_OFF     = 681344;    // u32[10*1024]
static const size_t MASK_OFF     = 759168;    // u64[10*16000]
// total ~2.04 MB

__device__ __forceinline__ int level_of(int a) {
  if (a < 120000) return 0;
  if (a < 150000) return 1;
  if (a < 157500) return 2;
  if (a < 159375) return 3;
  return 4;
}

// monotone decreasing transform: smaller d == larger score; d(-inf)=0xFF800000
__device__ __forceinline__ u32 dkey(float s) {
  u32 b = __float_as_uint(s);
  return (b & 0x80000000u) ? b : (~b & 0x7FFFFFFFu);
}
// exact inverse of dkey
__device__ __forceinline__ float dkey_inv(u32 d) {
  u32 b = (d & 0x80000000u) ? d : (~d & 0x7FFFFFFFu);
  return __uint_as_float(b);
}

// bit-exact replica of reference decode + clip + min-size check
__device__ __forceinline__ void decode_clip(const float* __restrict__ pred,
                                            const float* __restrict__ anch,
                                            const float* __restrict__ vs,
                                            int b, int a,
                                            float& x1c, float& y1c, float& x2c, float& y2c,
                                            bool& valid) {
  const float* pp = pred + ((size_t)b * A_TOT + (size_t)a) * 4;
  const float* aa = anch + (size_t)a * 4;
  float ax1 = aa[0], ay1 = aa[1], ax2 = aa[2], ay2 = aa[3];
  float px = pp[0], py = pp[1], pw = pp[2], ph = pp[3];
  float aw  = __fsub_rn(ax2, ax1);
  float ah  = __fsub_rn(ay2, ay1);
  float acx = __fadd_rn(ax1, __fmul_rn(0.5f, aw));
  float acy = __fadd_rn(ay1, __fmul_rn(0.5f, ah));
  float cx  = __fadd_rn(acx, __fmul_rn(px, aw));
  float cy  = __fadd_rn(acy, __fmul_rn(py, ah));
  float w   = __fmul_rn(expf(pw), aw);
  float h   = __fmul_rn(expf(ph), ah);
  float x1  = __fsub_rn(cx, __fmul_rn(0.5f, w));
  float y1  = __fsub_rn(cy, __fmul_rn(0.5f, h));
  float x2  = __fadd_rn(x1, w);
  float y2  = __fadd_rn(y1, h);
  float Wv = vs[b * 2 + 0], Hv = vs[b * 2 + 1];
  x1c = fminf(fmaxf(x1, 0.0f), Wv);
  y1c = fminf(fmaxf(y1, 0.0f), Hv);
  x2c = fminf(fmaxf(x2, 0.0f), Wv);
  y2c = fminf(fmaxf(y2, 0.0f), Hv);
  valid = (__fsub_rn(x2c, x1c) > 0.001f) && (__fsub_rn(y2c, y1c) > 0.001f);
}

__device__ __forceinline__ void bitonic_u64(u64* arr, int N, int t, int nt) {
  for (int k = 2; k <= N; k <<= 1) {
    for (int j = k >> 1; j > 0; j >>= 1) {
      __syncthreads();
      for (int i = t; i < N; i += nt) {
        int ixj = i ^ j;
        if (ixj > i) {
          u64 x = arr[i], y = arr[ixj];
          bool up = ((i & k) == 0);
          if (up ? (x > y) : (x < y)) { arr[i] = y; arr[ixj] = x; }
        }
      }
    }
  }
  __syncthreads();
}

__device__ __forceinline__ u64 shfl_xor_u64(u64 x, int lanemask) {
  u32 lo = (u32)x, hi = (u32)(x >> 32);
  lo = (u32)__shfl_xor((int)lo, lanemask);
  hi = (u32)__shfl_xor((int)hi, lanemask);
  return ((u64)hi << 32) | (u64)lo;
}

// bitonic sort of 2048 u64 keys: 2/thread over 1024 threads.
// j==1: in-register; 2<=j<=64: wave shuffle; j>=128: LDS double-buffered
// (one sync per LDS phase). Returns pointer to sorted LDS buffer.
__device__ __forceinline__ u64* regsort2048x(u64 v[2], int tid, u64* bufA, u64* bufB) {
  u64* bufs[2] = {bufA, bufB};
  int cur = 0;
  for (int k = 2; k <= 2048; k <<= 1) {
    for (int j = k >> 1; j > 0; j >>= 1) {
      if (j == 1) {
        bool up = (((2 * tid) & k) == 0);
        u64 a = v[0], b2 = v[1];
        bool sw = up ? (a > b2) : (a < b2);
        if (sw) { v[0] = b2; v[1] = a; }
      } else if (j <= 64) {
        int dl = j >> 1;
        bool up = (((2 * tid) & k) == 0);
        bool low = ((tid & dl) == 0);
        bool keepmin = (low == up);
#pragma unroll
        for (int e = 0; e < 2; ++e) {
          u64 o = shfl_xor_u64(v[e], dl);
          v[e] = keepmin ? (v[e] < o ? v[e] : o) : (v[e] > o ? v[e] : o);
        }
      } else {
        u64* B = bufs[cur]; cur ^= 1;
        B[2 * tid] = v[0]; B[2 * tid + 1] = v[1];
        __syncthreads();
#pragma unroll
        for (int e = 0; e < 2; ++e) {
          int i = 2 * tid + e, p = i ^ j;
          u64 o = B[p];
          bool up = ((i & k) == 0);
          bool keepmin = ((i < p) == up);
          v[e] = keepmin ? (v[e] < o ? v[e] : o) : (v[e] > o ? v[e] : o);
        }
      }
    }
  }
  u64* B = bufs[cur];
  B[2 * tid] = v[0]; B[2 * tid + 1] = v[1];
  __syncthreads();
  return B;
}

// ---------- 1) zero control + histogram region ----------
__global__ void k_zero(char* __restrict__ ws) {
  size_t i = (size_t)blockIdx.x * blockDim.x + threadIdx.x;
  if (i * 4 < ZERO_END) ((u32*)ws)[i] = 0u;
}

// ---------- 2) 12-bit histogram, LDS-privatized (<=2 segments/block) ----------
__global__ void k_hist12(const float* __restrict__ obj, char* __restrict__ ws) {
  __shared__ u32 h[2 * HB];   // 32 KB
  int tid = threadIdx.x;
  int b = blockIdx.x / NBH, loc = blockIdx.x % NBH;
  int start = loc * ABLK;
  int l0 = level_of(start);
  if (l0 >= 4) return;
  for (int i = tid; i < 2 * HB; i += 256) h[i] = 0u;
  __syncthreads();
  for (int it = 0; it < EPT; ++it) {
    int a = start + it * 256 + tid;
    if (a < A_TOT) {
      int l = level_of(a);
      if (l < 4) {
        u32 d = dkey(obj[(size_t)b * A_TOT + a]);
        atomicAdd(&h[(u32)(l - l0) * HB + (d >> 20)], 1u);
      }
    }
  }
  __syncthreads();
  int lend = level_of(min(start + ABLK - 1, A_TOT - 1));
  int nseg = ((l0 + 1 <= lend) && (l0 + 1 < 4)) ? 2 : 1;
  for (int s = 0; s < nseg; ++s) {
    u32* gh = (u32*)(ws + HIST12_OFF) + (size_t)(b * 4 + l0 + s) * HB;
    for (int i = tid; i < HB; i += 256) {
      u32 v = h[s * HB + i];
      if (v) atomicAdd(&gh[i], v);
    }
  }
}

// ---------- 3) inline cutoff + block-aggregated candidate append ----------
__global__ void k_compactsel(const float* __restrict__ obj, char* __restrict__ ws) {
  __shared__ u32 scan[256];
  __shared__ u32 cutv[2];
  __shared__ u32 lcnt[2], gbase[2];
  int tid = threadIdx.x, lane = tid & 63;
  int b = blockIdx.x / NBH, loc = blockIdx.x % NBH;
  int start = loc * ABLK;
  int l0 = level_of(start);
  if (l0 >= 4) return;
  int lend = level_of(min(start + ABLK - 1, A_TOT - 1));
  int nseg = ((l0 + 1 <= lend) && (l0 + 1 < 4)) ? 2 : 1;
  if (tid < 2) lcnt[tid] = 0;
  // recompute segment cutoffs from L2-resident hist (idempotent across blocks)
  for (int s = 0; s < nseg; ++s) {
    int seg = b * 4 + l0 + s;
    const u32* gh = (const u32*)(ws + HIST12_OFF) + (size_t)seg * HB;
    u32 vals[16]; u32 acc = 0;
    for (int q = 0; q < 16; ++q) { vals[q] = gh[tid * 16 + q]; acc += vals[q]; }
    __syncthreads();
    scan[tid] = acc; __syncthreads();
    for (int d = 1; d < 256; d <<= 1) {
      u32 x = (tid >= d) ? scan[tid - d] : 0u; __syncthreads();
      scan[tid] += x; __syncthreads();
    }
    u32 incl = scan[tid], prev = incl - acc;
    if (prev < KTOP && incl >= KTOP) {
      u32 run = prev; int cb = HB - 1;
      for (int q = 0; q < 16; ++q) { run += vals[q]; if (run >= KTOP) { cb = tid * 16 + q; break; } }
      cutv[s] = (u32)cb;
      ((u32*)(ws + CUT_OFF))[seg] = (u32)cb;
    }
  }
  __syncthreads();
  u32 dv[EPT], slotv[EPT], passm = 0, sim = 0;
  for (int it = 0; it < EPT; ++it) {
    int a = start + it * 256 + tid;
    bool pass = false; u32 si = 0, d = 0;
    if (a < A_TOT) {
      int l = level_of(a);
      if (l < 4) {
        si = (u32)(l - l0);
        d = dkey(obj[(size_t)b * A_TOT + a]);
        pass = (d >> 20) <= cutv[si];
      }
    }
    dv[it] = d;
    u64 mp = __ballot(pass);
    u64 m1 = __ballot(pass && si == 1);
    u64 m0 = mp & ~m1;
    u32 slot = 0;
    if (m0) {
      int ld = __builtin_ctzll(m0);
      u32 wb = 0;
      if (lane == ld) wb = atomicAdd(&lcnt[0], (u32)__popcll(m0));
      wb = __shfl(wb, ld);
      if (pass && si == 0) slot = wb + (u32)__popcll(m0 & ((1ull << lane) - 1ull));
    }
    if (m1) {
      int ld = __builtin_ctzll(m1);
      u32 wb = 0;
      if (lane == ld) wb = atomicAdd(&lcnt[1], (u32)__popcll(m1));
      wb = __shfl(wb, ld);
      if (pass && si == 1) slot = wb + (u32)__popcll(m1 & ((1ull << lane) - 1ull));
    }
    slotv[it] = slot;
    if (pass) { passm |= 1u << it; if (si) sim |= 1u << it; }
  }
  __syncthreads();
  if (tid < 2)
    gbase[tid] = lcnt[tid] ? atomicAdd((u32*)(ws + CCNT_OFF) + (b * 4 + l0 + tid), lcnt[tid]) : 0u;
  __syncthreads();
  for (int it = 0; it < EPT; ++it) {
    if ((passm >> it) & 1u) {
      int a = start + it * 256 + tid;
      u32 si = (sim >> it) & 1u;
      int seg = b * 4 + l0 + (int)si;
      u32 gslot = gbase[si] + slotv[it];
      if (gslot < CAND_CAP)
        // key = [dkey:32][anchor:18][slot:12] — slot below the anchor tie-break
        ((u64*)(ws + CAND_OFF))[(size_t)seg * CAND_CAP + gslot] =
            ((u64)dv[it] << 32) | ((u64)(u32)a << 12) | (u64)gslot;
    }
  }
}

// ---------- 4) per-(image,level): parallel gather-decode + register bitonic + compaction ----------
__global__ __launch_bounds__(1024)
void k_sortdec(const float* __restrict__ pred, const float* __restrict__ obj,
               const float* __restrict__ anch, const float* __restrict__ vs,
               char* __restrict__ ws) {
  __shared__ u64 bufAB[4096];        // 32 KB (double buffer / fallback array)
  __shared__ float4 dboxS[2048];     // 32 KB, indexed by slot
  __shared__ float dscS[2048];       // 8 KB
  __shared__ u32 validS[2048];       // 8 KB
  __shared__ u64 cm[16];
  u64* bufA = bufAB; u64* bufB = bufAB + 2048;
  int tid = threadIdx.x, lane = tid & 63, wv = tid >> 6;
  int P = blockIdx.x, b = P / 5, l = P % 5;
  int n;
  u64* S;
  if (l == 4) {
    n = 507;
    u64 v[2];
#pragma unroll
    for (int e = 0; e < 2; ++e) {
      int idx = 2 * tid + e;
      if (idx < 507) {
        int a = 159375 + idx;
        float sc = obj[(size_t)b * A_TOT + a];
        float x1, y1, x2, y2; bool valid;
        decode_clip(pred, anch, vs, b, a, x1, y1, x2, y2, valid);
        dboxS[idx] = make_float4(x1, y1, x2, y2);
        dscS[idx] = sc;
        validS[idx] = valid ? 1u : 0u;
        v[e] = ((u64)dkey(sc) << 32) | ((u64)(u32)a << 12) | (u64)idx;
      } else v[e] = ~0ull;
    }
    S = regsort2048x(v, tid, bufA, bufB);
  } else {
    n = KTOP;
    int seg = b * 4 + l;
    u32 cnt = min(((const u32*)(ws + CCNT_OFF))[seg], (u32)CAND_CAP);
    const u64* cand = (const u64*)(ws + CAND_OFF) + (size_t)seg * CAND_CAP;
    if (cnt <= 2048) {
      u64 v[2];
#pragma unroll
      for (int e = 0; e < 2; ++e) {
        int idx = 2 * tid + e;
        if (idx < (int)cnt) {
          u64 key = cand[idx];
          int a = (int)((key >> 12) & 0x3FFFFu);
          float x1, y1, x2, y2; bool valid;
          decode_clip(pred, anch, vs, b, a, x1, y1, x2, y2, valid);
          dboxS[idx] = make_float4(x1, y1, x2, y2);
          dscS[idx] = dkey_inv((u32)(key >> 32));
          validS[idx] = valid ? 1u : 0u;
          v[e] = key;
        } else v[e] = ~0ull;
      }
      S = regsort2048x(v, tid, bufA, bufB);
    } else {
      // safety fallback (statistically never taken: cnt ~= 1030)
      int N = 2048; while (N < (int)cnt) N <<= 1;
      for (int i = tid; i < N; i += 1024) bufAB[i] = (i < (int)cnt) ? cand[i] : ~0ull;
      bitonic_u64(bufAB, N, tid, 1024);
      for (int j = tid; j < KTOP; j += 1024) {
        u64 key = bufAB[j];
        int a = (int)((key >> 12) & 0x3FFFFu);
        float x1, y1, x2, y2; bool valid;
        decode_clip(pred, anch, vs, b, a, x1, y1, x2, y2, valid);
        dboxS[j] = make_float4(x1, y1, x2, y2);
        dscS[j] = dkey_inv((u32)(key >> 32));
        validS[j] = valid ? 1u : 0u;
        bufAB[j] = (key & ~0xFFFull) | (u64)j;   // rewrite slot = sorted pos
      }
      __syncthreads();
      S = bufAB;
    }
  }
  // max coord over the selected top-n (reference: max over selected boxes only)
  float m = 0.0f;
  for (int j = tid; j < n; j += 1024) {
    int slot = (int)(S[j] & 0xFFFull);
    float4 bx = dboxS[slot];
    m = fmaxf(m, fmaxf(fmaxf(bx.x, bx.y), fmaxf(bx.z, bx.w)));
  }
  for (int off = 32; off; off >>= 1) m = fmaxf(m, __shfl_xor(m, off));
  if (lane == 0) atomicMax((u32*)(ws + MAXC_OFF) + b, __float_as_uint(m));
  // stable valid-compaction, all 16 waves (wave w owns chunk w of 64)
  {
    int j = wv * 64 + lane;
    bool val = (j < n) && (validS[(int)(S[j] & 0xFFFull)] != 0u);
    u64 mask = __ballot(val);
    if (lane == 0) cm[wv] = mask;
    __syncthreads();
    int base = 0;
    for (int w2 = 0; w2 < wv; ++w2) base += __popcll(cm[w2]);
    if (val) {
      int r = base + __popcll(mask & ((1ull << lane) - 1ull));
      int slot = (int)(S[j] & 0xFFFull);
      ((u64*)(ws + LKEY2_OFF))[(size_t)P * 1024 + r] = S[j];
      ((float4*)(ws + LBOX_OFF))[(size_t)P * 1024 + r] = dboxS[slot];
      ((float*)(ws + LSC_OFF))[(size_t)P * 1024 + r] = dscS[slot];
    }
    if (tid == 0) {
      int tot = 0;
      for (int w2 = 0; w2 < 16; ++w2) tot += __popcll(cm[w2]);
      ((u32*)(ws + NV_OFF))[P] = (u32)tot;
    }
  }
}

__device__ __forceinline__ int lbound(const u64* __restrict__ arr, int n, u64 key) {
  int lo = 0, hi = n;
  while (lo < hi) { int mid = (lo + hi) >> 1; if (arr[mid] < key) lo = mid + 1; else hi = mid; }
  return lo;
}

// ---------- 5) distributed rank + LDS-staged suppression bitmask ----------
__global__ void k_maskrank(char* __restrict__ ws) {
  __shared__ float4 boxS[1024];   // 16 KB (offset applied)
  __shared__ float  areaS[1024];  //  4 KB (area of offset box)
  int tid = threadIdx.x, bid = blockIdx.x;
  int P = bid >> 6, rblk = bid & 63;
  int b = P / 5, l = P % 5;
  int n = (int)((const u32*)(ws + NV_OFF))[P];
  float M = __uint_as_float(((const u32*)(ws + MAXC_OFF))[b]);
  float maxc = __fadd_rn(M, 1.0f);
  float off = __fmul_rn((float)l, maxc);
  const float4* lbox = (const float4*)(ws + LBOX_OFF) + (size_t)P * 1024;
  for (int i = tid; i < n; i += 256) {
    float4 bx = lbox[i];
    bx.x = __fadd_rn(bx.x, off); bx.y = __fadd_rn(bx.y, off);
    bx.z = __fadd_rn(bx.z, off); bx.w = __fadd_rn(bx.w, off);
    boxS[i] = bx;
    areaS[i] = __fmul_rn(__fsub_rn(bx.z, bx.x), __fsub_rn(bx.w, bx.y));
  }
  // rank: this block's 16 elements, one per thread, 4 searches lock-step
  {
    int e = rblk * 16 + tid;
    if (tid < 16 && e < n) {
      const u64* lkey = (const u64*)(ws + LKEY2_OFF);
      const u32* nvp = (const u32*)(ws + NV_OFF);
      u64 key = lkey[(size_t)P * 1024 + e];
      const u64* base[4];
      int lo[4], hi[4], q2 = 0;
      for (int l2 = 0; l2 < 5; ++l2) {
        if (l2 == l) continue;
        base[q2] = lkey + (size_t)(b * 5 + l2) * 1024;
        lo[q2] = 0; hi[q2] = (int)nvp[b * 5 + l2];
        ++q2;
      }
      for (int step = 0; step < 11; ++step) {
#pragma unroll
        for (int q = 0; q < 4; ++q) {
          if (lo[q] < hi[q]) {
            int mid = (lo[q] + hi[q]) >> 1;
            u64 v = base[q][mid];
            if (v < key) lo[q] = mid + 1; else hi[q] = mid;
          }
        }
      }
      ((u32*)(ws + RANK_OFF))[(size_t)P * 1024 + e] =
          (u32)(e + lo[0] + lo[1] + lo[2] + lo[3]);
    }
  }
  __syncthreads();
  int i = rblk * 16 + (tid >> 4);
  int w = tid & 15;
  int W = (n + 63) >> 6;
  if (i >= n || w >= W) return;
  float4 bi = boxS[i];
  float ai = areaS[i];
  u64 word = 0;
  int j0 = w << 6;
  int jn = min(64, n - j0);
  if (jn == 64) {
#pragma unroll 4
    for (int t2 = 0; t2 < 64; ++t2) {
      int jj = (t2 + w) & 63;     // bank-conflict-free rotation
      float4 bj = boxS[j0 + jj];
      float xx1 = fmaxf(bi.x, bj.x);
      float yy1 = fmaxf(bi.y, bj.y);
      float xx2 = fminf(bi.z, bj.z);
      float yy2 = fminf(bi.w, bj.w);
      float iw = fmaxf(__fsub_rn(xx2, xx1), 0.0f);
      float ih = fmaxf(__fsub_rn(yy2, yy1), 0.0f);
      float inter = __fmul_rn(iw, ih);
      float den = __fadd_rn(__fsub_rn(__fadd_rn(ai, areaS[j0 + jj]), inter), 1e-9f);
      float iou = __fdiv_rn(inter, den);
      if (iou > 0.7f) word |= (1ull << jj);
    }
  } else {
    for (int jj = 0; jj < jn; ++jj) {
      float4 bj = boxS[j0 + jj];
      float xx1 = fmaxf(bi.x, bj.x);
      float yy1 = fmaxf(bi.y, bj.y);
      float xx2 = fminf(bi.z, bj.z);
      float yy2 = fminf(bi.w, bj.w);
      float iw = fmaxf(__fsub_rn(xx2, xx1), 0.0f);
      float ih = fmaxf(__fsub_rn(yy2, yy1), 0.0f);
      float inter = __fmul_rn(iw, ih);
      float den = __fadd_rn(__fsub_rn(__fadd_rn(ai, areaS[j0 + jj]), inter), 1e-9f);
      float iou = __fdiv_rn(inter, den);
      if (iou > 0.7f) word |= (1ull << jj);
    }
  }
  if (i >= j0 && i < j0 + 64) word &= ~(1ull << (i - j0));   // zero diagonal
  ((u64*)(ws + MASK_OFF))[(size_t)P * 16000 + (size_t)i * W + w] = word;
  if (word)
    atomicOr((u64*)(ws + CHUNKANY_OFF) + (size_t)P * 16 + (i >> 6), 1ull << (i & 63));
}

// ---------- 6) NMS scan (5 waves = 5 levels), latency-optimized + parallel emit ----------
__global__ __launch_bounds__(320)
void k_scanfin(float* __restrict__ out, char* __restrict__ ws) {
  __shared__ u64 keeps[5][16];
  __shared__ u64 kb[80];
  __shared__ u32 sb[128];
  __shared__ u32 pfx[80];
  __shared__ u32 nvs[5];
  int tid = threadIdx.x, w = tid >> 6, lane = tid & 63;
  int b = blockIdx.x;
  for (int i = tid; i < 80; i += 320) kb[i] = 0ull;
  for (int i = tid; i < 4000; i += 320) out[(size_t)b * 4000 + i] = 0.0f;
  for (int i = tid; i < 1000; i += 320) out[8000 + (size_t)b * 1000 + i] = 0.0f;
  if (tid < 5) nvs[tid] = ((const u32*)(ws + NV_OFF))[b * 5 + tid];

  int P = b * 5 + w;
  int n = (int)((const u32*)(ws + NV_OFF))[P];
  int W = (n + 63) >> 6;
  const u64* maskg = (const u64*)(ws + MASK_OFF) + (size_t)P * 16000;
  u64 ca = (lane < 16) ? ((const u64*)(ws + CHUNKANY_OFF))[(size_t)P * 16 + lane] : 0ull;
  u64 dpre[16];
#pragma unroll
  for (int c = 0; c < 16; ++c) {
    int row = (c << 6) + lane;
    dpre[c] = (c < W && row < n) ? maskg[(size_t)row * W + c] : 0ull;
  }
  u64 removed = 0ull, keepw = 0ull;
#pragma unroll
  for (int c = 0; c < 16; ++c) {
    if (c >= W) break;
    int rb = c << 6;
    int rows = min(64, n - rb);
    u64 rowsmask = (rows == 64) ? ~0ull : ((1ull << rows) - 1ull);
    u64 curw = __shfl(removed, c);
    u64 cand = ~curw & rowsmask;
    u64 ca_c = __shfl(ca, c);
    u64 keptbits;
    u64 anyrows = ca_c & cand;
    if (anyrows == 0ull) {
      keptbits = cand;
    } else {
      u64 diag = dpre[c];
      u64 diagnz = __ballot(diag != 0ull) & cand;
      if (diagnz == 0ull) {
        keptbits = cand;
      } else {
        u64 remw = curw | ~rowsmask;
        u64 kept = 0ull;
        int pos = 0;
        u64 work = diagnz;
        while (work) {
          int s = __builtin_ctzll(work); work &= work - 1;
          u64 range = (1ull << s) - (1ull << pos);
          kept |= ~remw & range;
          bool k = ((remw >> s) & 1ull) == 0ull;
          u64 dr = __shfl(diag, s);
          if (k) { kept |= 1ull << s; remw |= dr; }
          pos = s + 1;
        }
        u64 tail = (pos >= 64) ? 0ull : (~0ull << pos);
        kept |= ~remw & tail & rowsmask;
        keptbits = kept;
      }
      u64 todo = keptbits & ca_c;
      while (todo) {
        int r0 = __builtin_ctzll(todo); todo &= todo - 1;
        int r1 = -1, r2 = -1, r3 = -1;
        if (todo) { r1 = __builtin_ctzll(todo); todo &= todo - 1; }
        if (todo) { r2 = __builtin_ctzll(todo); todo &= todo - 1; }
        if (todo) { r3 = __builtin_ctzll(todo); todo &= todo - 1; }
        u64 v0 = 0, v1 = 0, v2 = 0, v3 = 0;
        if (lane < W) {
          v0 = maskg[(size_t)(rb + r0) * W + lane];
          if (r1 >= 0) v1 = maskg[(size_t)(rb + r1) * W + lane];
          if (r2 >= 0) v2 = maskg[(size_t)(rb + r2) * W + lane];
          if (r3 >= 0) v3 = maskg[(size_t)(rb + r3) * W + lane];
        }
        removed |= v0 | v1 | v2 | v3;
      }
    }
    if (lane == c) keepw |= keptbits;
  }
  if (lane < 16) keeps[w][lane] = keepw;
  __syncthreads();

  const u32* rank = (const u32*)(ws + RANK_OFF);
  for (int idx = tid; idx < 5120; idx += 320) {
    int p = idx >> 10, i = idx & 1023;
    if (i < (int)nvs[p] && ((keeps[p][i >> 6] >> (i & 63)) & 1ull)) {
      u32 r = rank[(size_t)(b * 5 + p) * 1024 + i];
      atomicOr(&kb[r >> 6], 1ull << (r & 63));
    }
  }
  __syncthreads();
  if (tid < 128) sb[tid] = (tid < 80) ? (u32)__popcll(kb[tid]) : 0u;
  __syncthreads();
  for (int d = 1; d < 128; d <<= 1) {
    u32 x = (tid < 128 && tid >= d) ? sb[tid - d] : 0u;
    __syncthreads();
    if (tid < 128) sb[tid] += x;
    __syncthreads();
  }
  if (tid < 80) pfx[tid] = sb[tid] - (u32)__popcll(kb[tid]);
  __syncthreads();
  for (int idx = tid; idx < 5120; idx += 320) {
    int p = idx >> 10, i = idx & 1023;
    if (i < (int)nvs[p] && ((keeps[p][i >> 6] >> (i & 63)) & 1ull)) {
      int Pp = b * 5 + p;
      u32 r = rank[(size_t)Pp * 1024 + i];
      u64 word = kb[r >> 6];
      int slot = (int)pfx[r >> 6] + __popcll(word & ((1ull << (r & 63)) - 1ull));
      if (slot < KTOP) {
        float4 bx = ((const float4*)(ws + LBOX_OFF))[(size_t)Pp * 1024 + i];
        float s = ((const float*)(ws + LSC_OFF))[(size_t)Pp * 1024 + i];
        float* ob = out + ((size_t)b * KTOP + slot) * 4;
        ob[0] = bx.x; ob[1] = bx.y; ob[2] = bx.z; ob[3] = bx.w;
        out[8000 + (size_t)b * KTOP + slot] = s;
      }
    }
  }
}

extern "C" void kernel_launch(void* const* d_in, const int* in_sizes, int n_in,
                              void* d_out, int out_size, void* d_ws, size_t ws_size,
                              hipStream_t stream) {
  const float* pred = (const float*)d_in[0];
  const float* obj  = (const float*)d_in[1];
  const float* anch = (const float*)d_in[2];
  const float* vs   = (const float*)d_in[3];
  float* out = (float*)d_out;
  char* ws = (char*)d_ws;
  (void)in_sizes; (void)n_in; (void)out_size; (void)ws_size;

  int gZ = (int)((ZERO_END / 4 + 255) / 256);
  k_zero      <<<gZ,        256, 0, stream>>>(ws);
  k_hist12    <<<BS * NBH,  256, 0, stream>>>(obj, ws);
  k_compactsel<<<BS * NBH,  256, 0, stream>>>(obj, ws);
  k_sortdec   <<<10,       1024, 0, stream>>>(pred, obj, anch, vs, ws);
  k_maskrank  <<<640,       256, 0, stream>>>(ws);
  k_scanfin   <<<2,         320, 0, stream>>>(out, ws);
}